// Round 1
// baseline (232.961 us; speedup 1.0000x reference)
//
#include <hip/hip_runtime.h>

#define HW 4608      // 48*96
#define NB 16
#define CC 256
#define SS 64
#define EPS 1e-5f
#define NSPLIT 24    // k_graph split-K

typedef __attribute__((ext_vector_type(8))) short short8;
typedef __attribute__((ext_vector_type(4))) float f32x4;

__device__ __forceinline__ ushort f2bf(float f) {
    uint u = __float_as_uint(f);
    return (ushort)((u + 0x7FFFu + ((u >> 16) & 1u)) >> 16);
}
__device__ __forceinline__ float bf2f(ushort h) {
    return __uint_as_float(((uint)h) << 16);
}

// ---------------- K0: pack W fragment-ready: Wf[cs][kq][r][j] bf16, c = cs*32+kq*8+j ----------
__global__ __launch_bounds__(256) void k_wf(const float* __restrict__ Ws,
                                            const float* __restrict__ Wp,
                                            ushort* __restrict__ Wf) {
    int idx = blockIdx.x * 256 + threadIdx.x;      // 0..32767
    int j = idx & 7, r = (idx >> 3) & 127, kq = (idx >> 10) & 3, cs = idx >> 12;
    int c = cs * 32 + kq * 8 + j;
    float v = (r < 64) ? Ws[r * CC + c] : Wp[(r - 64) * CC + c];
    Wf[idx] = f2bf(v);
}

// ---------------- K1: MFMA proj: [xs;E](128 x HW) = Wc @ x ; E=exp(gated); rsum atomics ------
// grid (36, NB), 256 thr (4 waves, 2x2). Block tile 128r x 128k, K=C=256 in 8 steps.
__global__ __launch_bounds__(256) void k_proj(const float* __restrict__ x,
                                              const ushort* __restrict__ Wf,
                                              const float* __restrict__ bs,
                                              const float* __restrict__ bp,
                                              const float* __restrict__ edge,
                                              ushort* __restrict__ xsb,
                                              ushort* __restrict__ Eb,
                                              float* __restrict__ rsum) {
    __shared__ __align__(16) ushort Bl[4 * 128 * 8];   // [kq][n][8] = 8 KB
    int n = blockIdx.y, k0 = blockIdx.x * 128;
    int tid = threadIdx.x, lane = tid & 63, w = tid >> 6;
    int wr = w >> 1, wn = w & 1;
    int q = lane >> 4, li = lane & 15;
    int sn = tid & 127, kq0 = (tid >> 7) * 2;
    f32x4 acc[4][4] = {};
    for (int cs = 0; cs < 8; cs++) {
        // stage x (fp32 -> bf16 fragment layout), conflict-free b128 writes
#pragma unroll
        for (int kk = 0; kk < 2; kk++) {
            int kq = kq0 + kk;
            union { ushort u[8]; uint4 v; } tmp;
#pragma unroll
            for (int j = 0; j < 8; j++) {
                float vv = x[((size_t)n * CC + cs * 32 + kq * 8 + j) * HW + k0 + sn];
                tmp.u[j] = f2bf(vv);
            }
            *(uint4*)&Bl[(kq * 128 + sn) * 8] = tmp.v;
        }
        __syncthreads();
        short8 af[4], bfr[4];
#pragma unroll
        for (int m = 0; m < 4; m++) {       // a-frags direct from global Wf (L2-hot)
            int r = wr * 64 + m * 16 + li;
            uint4 t = *(const uint4*)&Wf[((cs * 4 + q) * 128 + r) * 8];
            af[m] = *(short8*)&t;
        }
#pragma unroll
        for (int nn = 0; nn < 4; nn++) {
            int nl = wn * 64 + nn * 16 + li;
            uint4 t = *(const uint4*)&Bl[(q * 128 + nl) * 8];
            bfr[nn] = *(short8*)&t;
        }
#pragma unroll
        for (int m = 0; m < 4; m++)
#pragma unroll
            for (int nn = 0; nn < 4; nn++)
                acc[m][nn] = __builtin_amdgcn_mfma_f32_16x16x32_bf16(af[m], bfr[nn], acc[m][nn], 0, 0, 0);
        __syncthreads();
    }
    // epilogue: rows wr*64 + m*16 + q*4 + rr ; cols k0 + wn*64 + nn*16 + li
    if (wr == 0) {
#pragma unroll
        for (int m = 0; m < 4; m++) {
#pragma unroll
            for (int rr = 0; rr < 4; rr++) {
                int s = m * 16 + q * 4 + rr;
                float bv = bs[s];
#pragma unroll
                for (int nn = 0; nn < 4; nn++) {
                    int col = k0 + wn * 64 + nn * 16 + li;
                    xsb[((size_t)n * SS + s) * HW + col] = f2bf(acc[m][nn][rr] + bv);
                }
            }
        }
    } else {
        float ga[4];
#pragma unroll
        for (int nn = 0; nn < 4; nn++) {
            int col = k0 + wn * 64 + nn * 16 + li;
            float e0 = edge[((size_t)n * 2 + 0) * HW + col];
            float e1 = edge[((size_t)n * 2 + 1) * HW + col];
            ga[nn] = 1.f + 1.f / (1.f + __expf(e0 - e1));
        }
        float rp[4][4];
#pragma unroll
        for (int m = 0; m < 4; m++) {
#pragma unroll
            for (int rr = 0; rr < 4; rr++) {
                int s = m * 16 + q * 4 + rr;
                float bv = bp[s];
                float sum = 0.f;
#pragma unroll
                for (int nn = 0; nn < 4; nn++) {
                    int col = k0 + wn * 64 + nn * 16 + li;
                    float e = __expf((acc[m][nn][rr] + bv) * ga[nn]);
                    sum += e;
                    Eb[((size_t)n * SS + s) * HW + col] = f2bf(e);
                }
                rp[m][rr] = sum;
            }
        }
#pragma unroll
        for (int b = 1; b < 16; b <<= 1)
#pragma unroll
            for (int m = 0; m < 4; m++)
#pragma unroll
                for (int rr = 0; rr < 4; rr++)
                    rp[m][rr] += __shfl_xor(rp[m][rr], b, 64);
        if (li == 0) {
#pragma unroll
            for (int m = 0; m < 4; m++)
#pragma unroll
                for (int rr = 0; rr < 4; rr++)
                    atomicAdd(&rsum[n * SS + m * 16 + q * 4 + rr], rp[m][rr]);
        }
    }
}

// ---------------- K2: MFMA graph: U = xs@E^T, P = E@E^T, split-K partials, NO LDS -----------
// grid (NSPLIT, NB). Waves 0,1: U halves; waves 2,3: P halves. K/block = HW/NSPLIT = 192.
__global__ __launch_bounds__(256) void k_graph(const ushort* __restrict__ xsb,
                                               const ushort* __restrict__ Eb,
                                               float* __restrict__ Up,
                                               float* __restrict__ Pp) {
    int n = blockIdx.y, sp = blockIdx.x;
    int kbase = sp * (HW / NSPLIT);
    int tid = threadIdx.x, lane = tid & 63, w = tid >> 6;
    int q = lane >> 4, li = lane & 15;
    bool isP = w >= 2;
    int half = w & 1;
    const ushort* Arow = isP ? Eb : xsb;
    f32x4 acc[2][4] = {};
    for (int ks = 0; ks < (HW / NSPLIT) / 32; ks++) {
        int kb = kbase + ks * 32 + q * 8;
        short8 af[2], bfr[4];
#pragma unroll
        for (int mt = 0; mt < 2; mt++) {
            int s = half * 32 + mt * 16 + li;
            uint4 t = *(const uint4*)&Arow[((size_t)n * SS + s) * HW + kb];
            af[mt] = *(short8*)&t;
        }
#pragma unroll
        for (int nt = 0; nt < 4; nt++) {
            int tt = nt * 16 + li;
            uint4 t = *(const uint4*)&Eb[((size_t)n * SS + tt) * HW + kb];
            bfr[nt] = *(short8*)&t;
        }
#pragma unroll
        for (int mt = 0; mt < 2; mt++)
#pragma unroll
            for (int nt = 0; nt < 4; nt++)
                acc[mt][nt] = __builtin_amdgcn_mfma_f32_16x16x32_bf16(af[mt], bfr[nt], acc[mt][nt], 0, 0, 0);
    }
    float* dst = (isP ? Pp : Up) + ((size_t)sp * NB + n) * 4096;
#pragma unroll
    for (int mt = 0; mt < 2; mt++)
#pragma unroll
        for (int nt = 0; nt < 4; nt++)
#pragma unroll
            for (int rr = 0; rr < 4; rr++) {
                int row = half * 32 + mt * 16 + q * 4 + rr;
                int col = nt * 16 + li;
                dst[row * 64 + col] = acc[mt][nt][rr];
            }
}

// ---------------- K2b: reduce split-K partials (float4 vectorized) ----------------
__global__ __launch_bounds__(256) void k_red(const float* __restrict__ Up,
                                             const float* __restrict__ Pp,
                                             float* __restrict__ U,
                                             float* __restrict__ P) {
    int idx = blockIdx.x * 256 + threadIdx.x;    // 0..32767, each handles one float4
    const float* src = (idx < 16384) ? Up : Pp;
    float* dst = (idx < 16384) ? U : P;
    int o = (idx & 16383) * 4;
    f32x4 s = {};
    for (int sp = 0; sp < NSPLIT; sp++) {
        f32x4 v = *(const f32x4*)&src[(size_t)sp * 65536 + o];
        s += v;
    }
    *(f32x4*)&dst[o] = s;
}

// ---------------- K3: GCN + fold We: M' fp32 [c][t] AND bf16 fragment-ready Mf --------------
__global__ __launch_bounds__(256) void k_gcn(const float* __restrict__ U,
                                             const float* __restrict__ rsum,
                                             const float* __restrict__ W1,
                                             const float* __restrict__ W2,
                                             const float* __restrict__ We,
                                             float* __restrict__ M,
                                             ushort* __restrict__ Mf) {
    __shared__ __align__(16) float A[64 * 68];
    __shared__ __align__(16) float B[64 * 68];
    __shared__ __align__(16) float Cb[64 * 68];
    __shared__ float rs[64];
    int n = blockIdx.x;
    int cc = blockIdx.y;
    int tid = threadIdx.x;
    int t0 = tid >> 4, t1 = tid & 15;
    if (tid < 64) rs[tid] = 1.0f / rsum[n * SS + tid];
    __syncthreads();
#pragma unroll
    for (int i = 0; i < 16; i++) {
        int idx = tid + i * 256;
        int r = idx >> 6, cth = idx & 63;
        A[cth * 68 + r] = U[n * 4096 + idx] * rs[cth];
        B[cth * 68 + r] = W1[idx];
    }
    __syncthreads();
    {
        float acc[4][4] = {};
        for (int j = 0; j < 64; j++) {
            float4 a4 = *(const float4*)&A[j * 68 + t0 * 4];
            float4 b4 = *(const float4*)&B[j * 68 + t1 * 4];
            float a[4] = {a4.x, a4.y, a4.z, a4.w};
            float b[4] = {b4.x, b4.y, b4.z, b4.w};
#pragma unroll
            for (int p = 0; p < 4; p++)
#pragma unroll
                for (int qq = 0; qq < 4; qq++) acc[p][qq] += a[p] * b[qq];
        }
#pragma unroll
        for (int p = 0; p < 4; p++)
#pragma unroll
            for (int qq = 0; qq < 4; qq++) {
                acc[p][qq] -= A[(t1 * 4 + qq) * 68 + (t0 * 4 + p)];
                Cb[(t0 * 4 + p) * 68 + t1 * 4 + qq] = acc[p][qq];
            }
    }
    __syncthreads();
#pragma unroll
    for (int i = 0; i < 16; i++) {
        int idx = tid + i * 256;
        int r = idx >> 6, cth = idx & 63;
        B[cth * 68 + r] = W2[idx];
    }
    __syncthreads();
    {
        float acc[4][4] = {};
        for (int j = 0; j < 64; j++) {
            float4 a4 = *(const float4*)&B[j * 68 + t0 * 4];
            float4 b4 = *(const float4*)&Cb[j * 68 + t1 * 4];
            float a[4] = {a4.x, a4.y, a4.z, a4.w};
            float b[4] = {b4.x, b4.y, b4.z, b4.w};
#pragma unroll
            for (int p = 0; p < 4; p++)
#pragma unroll
                for (int qq = 0; qq < 4; qq++) acc[p][qq] += a[p] * b[qq];
        }
        __syncthreads();
#pragma unroll
        for (int p = 0; p < 4; p++)
#pragma unroll
            for (int qq = 0; qq < 4; qq++)
                A[(t0 * 4 + p) * 68 + t1 * 4 + qq] = fmaxf(acc[p][qq], 0.f);
    }
    __syncthreads();
#pragma unroll
    for (int i = 0; i < 16; i++) {
        int idx = tid + i * 256;
        int c = idx >> 6, j = idx & 63;
        B[j * 68 + c] = We[(cc * 64 + c) * 64 + j];
    }
    __syncthreads();
    {
        float acc[4][4] = {};
        for (int j = 0; j < 64; j++) {
            float4 a4 = *(const float4*)&B[j * 68 + t0 * 4];
            float4 b4 = *(const float4*)&A[j * 68 + t1 * 4];
            float a[4] = {a4.x, a4.y, a4.z, a4.w};
            float b[4] = {b4.x, b4.y, b4.z, b4.w};
#pragma unroll
            for (int p = 0; p < 4; p++)
#pragma unroll
                for (int qq = 0; qq < 4; qq++) acc[p][qq] += a[p] * b[qq];
        }
#pragma unroll
        for (int p = 0; p < 4; p++) {
            int c = cc * 64 + t0 * 4 + p;
            float v[4];
#pragma unroll
            for (int qq = 0; qq < 4; qq++) v[qq] = acc[p][qq] * rs[t1 * 4 + qq];
            float4 st = {v[0], v[1], v[2], v[3]};
            *(float4*)&M[((size_t)n * CC + c) * 64 + t1 * 4] = st;
#pragma unroll
            for (int qq = 0; qq < 4; qq++) {
                int t = t1 * 4 + qq;
                Mf[(size_t)n * 16384 + ((t >> 3) * 256 + c) * 8 + (t & 7)] = f2bf(v[qq]);
            }
        }
    }
}

// ---------------- K4: BN stats -> scale/bias (all-n LDS preload, 2-barrier body) ----------------
__global__ __launch_bounds__(256) void k_stats(const float* __restrict__ M,
                                               const float* __restrict__ P,
                                               const float* __restrict__ rsum,
                                               const float* __restrict__ gamma,
                                               const float* __restrict__ beta,
                                               float* __restrict__ sc,
                                               float* __restrict__ bi) {
    __shared__ float ms[NB][64];     // 4 KB: M rows for this channel, all n
    __shared__ float red[256];
    int c = blockIdx.x;
    int tid = threadIdx.x;
    for (int i = tid; i < NB * 64; i += 256) {
        int n = i >> 6, s = i & 63;
        ms[n][s] = M[((size_t)n * CC + c) * 64 + s];
    }
    __syncthreads();
    // qa = sum_n m_n^T P_n m_n   (each thread strided over the 4096 P-entries per n)
    float qa = 0.f;
    for (int n = 0; n < NB; n++) {
        const float* Pn = P + n * 4096;
#pragma unroll
        for (int p = 0; p < 16; p++) {
            int e = p * 256 + tid;
            qa += ms[n][e >> 6] * ms[n][e & 63] * Pn[e];
        }
    }
    // sa = sum_n sum_s ms[n][s] * rsum[n][s]  (parallel over all 256 threads)
    float sa = 0.f;
    for (int i = tid; i < NB * 64; i += 256) {
        int n = i >> 6, s = i & 63;
        sa += ms[n][s] * rsum[n * SS + s];
    }
    red[tid] = qa;
    __syncthreads();
    for (int off = 128; off > 0; off >>= 1) {
        if (tid < off) red[tid] += red[tid + off];
        __syncthreads();
    }
    float qtot = red[0];
    __syncthreads();
    red[tid] = sa;
    __syncthreads();
    for (int off = 128; off > 0; off >>= 1) {
        if (tid < off) red[tid] += red[tid + off];
        __syncthreads();
    }
    if (tid == 0) {
        float stot = red[0];
        const float invM = 1.0f / ((float)NB * (float)HW);
        float mean = stot * invM;
        float var = qtot * invM - mean * mean;
        float s = gamma[c] * rsqrtf(var + EPS);
        sc[c] = s;
        bi[c] = beta[c] - s * mean;
    }
}

// ---------------- K5: MFMA out: out = x + sc[c]*(M' @ E)[c,k] + bi[c] ----------------
// grid (72, NB): block 256c x 64hw, K=64 (2 MFMA steps). A direct from Mf; B via LDS.
__global__ __launch_bounds__(256) void k_out(const float* __restrict__ x,
                                             const ushort* __restrict__ Mf,
                                             const ushort* __restrict__ Eb,
                                             const float* __restrict__ sc,
                                             const float* __restrict__ bi,
                                             float* __restrict__ out) {
    __shared__ __align__(16) ushort Bl[8 * 64 * 8];    // [kq][n][8] = 8 KB
    int n = blockIdx.y, k0 = blockIdx.x * 64;
    int tid = threadIdx.x, lane = tid & 63, w = tid >> 6;
    int q = lane >> 4, li = lane & 15;
    {
        int nl = tid & 63, pr = tid >> 6;
#pragma unroll
        for (int kk = 0; kk < 2; kk++) {
            int kq = pr * 2 + kk;
            union { ushort u[8]; uint4 v; } tmp;
#pragma unroll
            for (int j = 0; j < 8; j++)
                tmp.u[j] = Eb[((size_t)n * SS + kq * 8 + j) * HW + k0 + nl];
            *(uint4*)&Bl[(kq * 64 + nl) * 8] = tmp.v;
        }
    }
    __syncthreads();
    f32x4 acc[4][4] = {};
#pragma unroll
    for (int ks = 0; ks < 2; ks++) {
        short8 af[4], bfr[4];
#pragma unroll
        for (int mt = 0; mt < 4; mt++) {
            int c = w * 64 + mt * 16 + li;
            uint4 t = *(const uint4*)&Mf[(size_t)n * 16384 + ((ks * 4 + q) * 256 + c) * 8];
            af[mt] = *(short8*)&t;
        }
#pragma unroll
        for (int nt = 0; nt < 4; nt++) {
            int nl = nt * 16 + li;
            uint4 t = *(const uint4*)&Bl[((ks * 4 + q) * 64 + nl) * 8];
            bfr[nt] = *(short8*)&t;
        }
#pragma unroll
        for (int mt = 0; mt < 4; mt++)
#pragma unroll
            for (int nt = 0; nt < 4; nt++)
                acc[mt][nt] = __builtin_amdgcn_mfma_f32_16x16x32_bf16(af[mt], bfr[nt], acc[mt][nt], 0, 0, 0);
    }
#pragma unroll
    for (int mt = 0; mt < 4; mt++) {
#pragma unroll
        for (int rr = 0; rr < 4; rr++) {
            int c = w * 64 + mt * 16 + q * 4 + rr;
            float s_ = sc[c], bv = bi[c];
            size_t base = ((size_t)n * CC + c) * HW + k0;
#pragma unroll
            for (int nt = 0; nt < 4; nt++) {
                int col = nt * 16 + li;
                out[base + col] = x[base + col] + s_ * acc[mt][nt][rr] + bv;
            }
        }
    }
}

extern "C" void kernel_launch(void* const* d_in, const int* in_sizes, int n_in,
                              void* d_out, int out_size, void* d_ws, size_t ws_size,
                              hipStream_t stream) {
    const float* x = (const float*)d_in[0];
    const float* edge = (const float*)d_in[1];
    const float* Ws = (const float*)d_in[2];
    const float* bs = (const float*)d_in[3];
    const float* Wp = (const float*)d_in[4];
    const float* bp = (const float*)d_in[5];
    const float* W1 = (const float*)d_in[6];
    const float* W2 = (const float*)d_in[7];
    const float* We = (const float*)d_in[8];
    const float* gamma = (const float*)d_in[9];
    const float* beta = (const float*)d_in[10];
    float* out = (float*)d_out;

    char* base = (char*)d_ws;
    ushort* Wf  = (ushort*)base;                    base += 65536;           // 64 KB
    ushort* xsb = (ushort*)base;                    base += 9437184;         // 9 MB
    ushort* Eb  = (ushort*)base;                    base += 9437184;
    float*  Up  = (float*)base;                     base += (size_t)NSPLIT * NB * 4096 * 4;
    float*  Pp  = (float*)base;                     base += (size_t)NSPLIT * NB * 4096 * 4;
    float*  U   = (float*)base;                     base += 262144;
    float*  P   = (float*)base;                     base += 262144;
    float*  rsum= (float*)base;                     base += 4096;
    float*  M   = (float*)base;                     base += 1048576;
    ushort* Mf  = (ushort*)base;                    base += 524288;
    float*  sc  = (float*)base;                     base += 1024;
    float*  bi  = (float*)base;                     base += 1024;

    hipMemsetAsync(rsum, 0, 1024 * sizeof(float), stream);
    k_wf<<<128, 256, 0, stream>>>(Ws, Wp, Wf);
    k_proj<<<dim3(36, NB), 256, 0, stream>>>(x, Wf, bs, bp, edge, xsb, Eb, rsum);
    k_graph<<<dim3(NSPLIT, NB), 256, 0, stream>>>(xsb, Eb, Up, Pp);
    k_red<<<128, 256, 0, stream>>>(Up, Pp, U, P);
    k_gcn<<<dim3(NB, 4), 256, 0, stream>>>(U, rsum, W1, W2, We, M, Mf);
    k_stats<<<256, 256, 0, stream>>>(M, P, rsum, gamma, beta, sc, bi);
    k_out<<<dim3(72, NB), 256, 0, stream>>>(x, Mf, Eb, sc, bi, out);
}

// Round 3
// 223.415 us; speedup vs baseline: 1.0427x; 1.0427x over previous
//
#include <hip/hip_runtime.h>

#define HW 4608      // 48*96
#define NB 16
#define CC 256
#define SS 64
#define EPS 1e-5f
#define NSPLIT 24    // k_graph split-K

typedef __attribute__((ext_vector_type(8))) short short8;
typedef __attribute__((ext_vector_type(4))) float f32x4;

__device__ __forceinline__ ushort f2bf(float f) {
    uint u = __float_as_uint(f);
    return (ushort)((u + 0x7FFFu + ((u >> 16) & 1u)) >> 16);
}
__device__ __forceinline__ float bf2f(ushort h) {
    return __uint_as_float(((uint)h) << 16);
}

// ---------------- K0: pack W fragment-ready: Wf[cs][kq][r][j] bf16, c = cs*32+kq*8+j ----------
__global__ __launch_bounds__(256) void k_wf(const float* __restrict__ Ws,
                                            const float* __restrict__ Wp,
                                            ushort* __restrict__ Wf) {
    int idx = blockIdx.x * 256 + threadIdx.x;      // 0..32767
    int j = idx & 7, r = (idx >> 3) & 127, kq = (idx >> 10) & 3, cs = idx >> 12;
    int c = cs * 32 + kq * 8 + j;
    float v = (r < 64) ? Ws[r * CC + c] : Wp[(r - 64) * CC + c];
    Wf[idx] = f2bf(v);
}

// ---------------- K1: MFMA proj v2: 128r x 64k tile, register-prefetch pipeline --------------
// grid (72, NB), 256 thr (4 waves). Wave w owns rows w*32..w*32+31. K=C=256 in 8 steps.
// Per iter: consume prefetched x+Wf regs -> LDS/frags; issue next-iter loads before MFMA so
// the MFMA phase has no VMEM wait; only vmcnt drain is at iteration top (in-order VMEM).
__global__ __launch_bounds__(256) void k_proj(const float* __restrict__ x,
                                              const ushort* __restrict__ Wf,
                                              const float* __restrict__ bs,
                                              const float* __restrict__ bp,
                                              const float* __restrict__ edge,
                                              ushort* __restrict__ xsb,
                                              ushort* __restrict__ Eb,
                                              float* __restrict__ rsum) {
    __shared__ __align__(16) ushort Bl[4 * 64 * 8];   // [kq][col][8] = 4 KB
    int n = blockIdx.y, k0 = blockIdx.x * 64;
    int tid = threadIdx.x, lane = tid & 63, w = tid >> 6;
    int q = lane >> 4, li = lane & 15;
    f32x4 acc[2][4] = {};
    const float* xb = x + (size_t)n * CC * HW + k0 + lane;  // staging: col=lane, ch-group kq=w
    float pf[8];
    uint4 afn[2];
    // prologue: issue loads for cs=0 (x staging values + A-fragments)
#pragma unroll
    for (int j = 0; j < 8; j++) pf[j] = xb[(size_t)(w * 8 + j) * HW];
#pragma unroll
    for (int mt = 0; mt < 2; mt++)
        afn[mt] = *(const uint4*)&Wf[((0 * 4 + q) * 128 + w * 32 + mt * 16 + li) * 8];
#pragma unroll 1
    for (int cs = 0; cs < 8; cs++) {
        // consume prefetched regs
        union { ushort u[8]; uint4 v; } tmp;
#pragma unroll
        for (int j = 0; j < 8; j++) tmp.u[j] = f2bf(pf[j]);
        short8 af[2];
        af[0] = *(short8*)&afn[0];
        af[1] = *(short8*)&afn[1];
        *(uint4*)&Bl[(w * 64 + lane) * 8] = tmp.v;
        __syncthreads();
        // issue next-iter global loads (hidden under ds_read + MFMA + barriers)
        if (cs < 7) {
#pragma unroll
            for (int j = 0; j < 8; j++)
                pf[j] = xb[(size_t)((cs + 1) * 32 + w * 8 + j) * HW];
#pragma unroll
            for (int mt = 0; mt < 2; mt++)
                afn[mt] = *(const uint4*)&Wf[(((cs + 1) * 4 + q) * 128 + w * 32 + mt * 16 + li) * 8];
        }
        short8 bfr[4];
#pragma unroll
        for (int nt = 0; nt < 4; nt++) {
            uint4 t = *(const uint4*)&Bl[(q * 64 + nt * 16 + li) * 8];
            bfr[nt] = *(short8*)&t;
        }
#pragma unroll
        for (int mt = 0; mt < 2; mt++)
#pragma unroll
            for (int nt = 0; nt < 4; nt++)
                acc[mt][nt] = __builtin_amdgcn_mfma_f32_16x16x32_bf16(af[mt], bfr[nt], acc[mt][nt], 0, 0, 0);
        __syncthreads();
    }
    // epilogue: rows w*32 + mt*16 + q*4 + rr ; cols k0 + nt*16 + li
    if (w < 2) {
#pragma unroll
        for (int mt = 0; mt < 2; mt++) {
#pragma unroll
            for (int rr = 0; rr < 4; rr++) {
                int s = w * 32 + mt * 16 + q * 4 + rr;
                float bv = bs[s];
#pragma unroll
                for (int nt = 0; nt < 4; nt++) {
                    int col = k0 + nt * 16 + li;
                    xsb[((size_t)n * SS + s) * HW + col] = f2bf(acc[mt][nt][rr] + bv);
                }
            }
        }
    } else {
        float ga[4];
#pragma unroll
        for (int nt = 0; nt < 4; nt++) {
            int col = k0 + nt * 16 + li;
            float e0 = edge[((size_t)n * 2 + 0) * HW + col];
            float e1 = edge[((size_t)n * 2 + 1) * HW + col];
            ga[nt] = 1.f + 1.f / (1.f + __expf(e0 - e1));
        }
        float rp[2][4];
#pragma unroll
        for (int mt = 0; mt < 2; mt++) {
#pragma unroll
            for (int rr = 0; rr < 4; rr++) {
                int s = (w - 2) * 32 + mt * 16 + q * 4 + rr;
                float bv = bp[s];
                float sum = 0.f;
#pragma unroll
                for (int nt = 0; nt < 4; nt++) {
                    int col = k0 + nt * 16 + li;
                    float e = __expf((acc[mt][nt][rr] + bv) * ga[nt]);
                    sum += e;
                    Eb[((size_t)n * SS + s) * HW + col] = f2bf(e);
                }
                rp[mt][rr] = sum;
            }
        }
#pragma unroll
        for (int b = 1; b < 16; b <<= 1)
#pragma unroll
            for (int mt = 0; mt < 2; mt++)
#pragma unroll
                for (int rr = 0; rr < 4; rr++)
                    rp[mt][rr] += __shfl_xor(rp[mt][rr], b, 64);
        if (li == 0) {
#pragma unroll
            for (int mt = 0; mt < 2; mt++)
#pragma unroll
                for (int rr = 0; rr < 4; rr++)
                    atomicAdd(&rsum[n * SS + (w - 2) * 32 + mt * 16 + q * 4 + rr], rp[mt][rr]);
        }
    }
}

// ---------------- K2: MFMA graph: U = xs@E^T, P = E@E^T, split-K partials, NO LDS -----------
// grid (NSPLIT, NB). Waves 0,1: U halves; waves 2,3: P halves. K/block = HW/NSPLIT = 192.
__global__ __launch_bounds__(256) void k_graph(const ushort* __restrict__ xsb,
                                               const ushort* __restrict__ Eb,
                                               float* __restrict__ Up,
                                               float* __restrict__ Pp) {
    int n = blockIdx.y, sp = blockIdx.x;
    int kbase = sp * (HW / NSPLIT);
    int tid = threadIdx.x, lane = tid & 63, w = tid >> 6;
    int q = lane >> 4, li = lane & 15;
    bool isP = w >= 2;
    int half = w & 1;
    const ushort* Arow = isP ? Eb : xsb;
    f32x4 acc[2][4] = {};
    for (int ks = 0; ks < (HW / NSPLIT) / 32; ks++) {
        int kb = kbase + ks * 32 + q * 8;
        short8 af[2], bfr[4];
#pragma unroll
        for (int mt = 0; mt < 2; mt++) {
            int s = half * 32 + mt * 16 + li;
            uint4 t = *(const uint4*)&Arow[((size_t)n * SS + s) * HW + kb];
            af[mt] = *(short8*)&t;
        }
#pragma unroll
        for (int nt = 0; nt < 4; nt++) {
            int tt = nt * 16 + li;
            uint4 t = *(const uint4*)&Eb[((size_t)n * SS + tt) * HW + kb];
            bfr[nt] = *(short8*)&t;
        }
#pragma unroll
        for (int mt = 0; mt < 2; mt++)
#pragma unroll
            for (int nt = 0; nt < 4; nt++)
                acc[mt][nt] = __builtin_amdgcn_mfma_f32_16x16x32_bf16(af[mt], bfr[nt], acc[mt][nt], 0, 0, 0);
    }
    float* dst = (isP ? Pp : Up) + ((size_t)sp * NB + n) * 4096;
#pragma unroll
    for (int mt = 0; mt < 2; mt++)
#pragma unroll
        for (int nt = 0; nt < 4; nt++)
#pragma unroll
            for (int rr = 0; rr < 4; rr++) {
                int row = half * 32 + mt * 16 + q * 4 + rr;
                int col = nt * 16 + li;
                dst[row * 64 + col] = acc[mt][nt][rr];
            }
}

// ---------------- K2b: reduce split-K partials (float4 vectorized) ----------------
__global__ __launch_bounds__(256) void k_red(const float* __restrict__ Up,
                                             const float* __restrict__ Pp,
                                             float* __restrict__ U,
                                             float* __restrict__ P) {
    int idx = blockIdx.x * 256 + threadIdx.x;    // 0..32767, each handles one float4
    const float* src = (idx < 16384) ? Up : Pp;
    float* dst = (idx < 16384) ? U : P;
    int o = (idx & 16383) * 4;
    f32x4 s = {};
    for (int sp = 0; sp < NSPLIT; sp++) {
        f32x4 v = *(const f32x4*)&src[(size_t)sp * 65536 + o];
        s += v;
    }
    *(f32x4*)&dst[o] = s;
}

// ---------------- K3: GCN + fold We: M' fp32 [c][t] AND bf16 fragment-ready Mf --------------
__global__ __launch_bounds__(256) void k_gcn(const float* __restrict__ U,
                                             const float* __restrict__ rsum,
                                             const float* __restrict__ W1,
                                             const float* __restrict__ W2,
                                             const float* __restrict__ We,
                                             float* __restrict__ M,
                                             ushort* __restrict__ Mf) {
    __shared__ __align__(16) float A[64 * 68];
    __shared__ __align__(16) float B[64 * 68];
    __shared__ __align__(16) float Cb[64 * 68];
    __shared__ float rs[64];
    int n = blockIdx.x;
    int cc = blockIdx.y;
    int tid = threadIdx.x;
    int t0 = tid >> 4, t1 = tid & 15;
    if (tid < 64) rs[tid] = 1.0f / rsum[n * SS + tid];
    __syncthreads();
#pragma unroll
    for (int i = 0; i < 16; i++) {
        int idx = tid + i * 256;
        int r = idx >> 6, cth = idx & 63;
        A[cth * 68 + r] = U[n * 4096 + idx] * rs[cth];
        B[cth * 68 + r] = W1[idx];
    }
    __syncthreads();
    {
        float acc[4][4] = {};
        for (int j = 0; j < 64; j++) {
            float4 a4 = *(const float4*)&A[j * 68 + t0 * 4];
            float4 b4 = *(const float4*)&B[j * 68 + t1 * 4];
            float a[4] = {a4.x, a4.y, a4.z, a4.w};
            float b[4] = {b4.x, b4.y, b4.z, b4.w};
#pragma unroll
            for (int p = 0; p < 4; p++)
#pragma unroll
                for (int qq = 0; qq < 4; qq++) acc[p][qq] += a[p] * b[qq];
        }
#pragma unroll
        for (int p = 0; p < 4; p++)
#pragma unroll
            for (int qq = 0; qq < 4; qq++) {
                acc[p][qq] -= A[(t1 * 4 + qq) * 68 + (t0 * 4 + p)];
                Cb[(t0 * 4 + p) * 68 + t1 * 4 + qq] = acc[p][qq];
            }
    }
    __syncthreads();
#pragma unroll
    for (int i = 0; i < 16; i++) {
        int idx = tid + i * 256;
        int r = idx >> 6, cth = idx & 63;
        B[cth * 68 + r] = W2[idx];
    }
    __syncthreads();
    {
        float acc[4][4] = {};
        for (int j = 0; j < 64; j++) {
            float4 a4 = *(const float4*)&B[j * 68 + t0 * 4];
            float4 b4 = *(const float4*)&Cb[j * 68 + t1 * 4];
            float a[4] = {a4.x, a4.y, a4.z, a4.w};
            float b[4] = {b4.x, b4.y, b4.z, b4.w};
#pragma unroll
            for (int p = 0; p < 4; p++)
#pragma unroll
                for (int qq = 0; qq < 4; qq++) acc[p][qq] += a[p] * b[qq];
        }
        __syncthreads();
#pragma unroll
        for (int p = 0; p < 4; p++)
#pragma unroll
            for (int qq = 0; qq < 4; qq++)
                A[(t0 * 4 + p) * 68 + t1 * 4 + qq] = fmaxf(acc[p][qq], 0.f);
    }
    __syncthreads();
#pragma unroll
    for (int i = 0; i < 16; i++) {
        int idx = tid + i * 256;
        int c = idx >> 6, j = idx & 63;
        B[j * 68 + c] = We[(cc * 64 + c) * 64 + j];
    }
    __syncthreads();
    {
        float acc[4][4] = {};
        for (int j = 0; j < 64; j++) {
            float4 a4 = *(const float4*)&B[j * 68 + t0 * 4];
            float4 b4 = *(const float4*)&A[j * 68 + t1 * 4];
            float a[4] = {a4.x, a4.y, a4.z, a4.w};
            float b[4] = {b4.x, b4.y, b4.z, b4.w};
#pragma unroll
            for (int p = 0; p < 4; p++)
#pragma unroll
                for (int qq = 0; qq < 4; qq++) acc[p][qq] += a[p] * b[qq];
        }
#pragma unroll
        for (int p = 0; p < 4; p++) {
            int c = cc * 64 + t0 * 4 + p;
            float v[4];
#pragma unroll
            for (int qq = 0; qq < 4; qq++) v[qq] = acc[p][qq] * rs[t1 * 4 + qq];
            float4 st = {v[0], v[1], v[2], v[3]};
            *(float4*)&M[((size_t)n * CC + c) * 64 + t1 * 4] = st;
#pragma unroll
            for (int qq = 0; qq < 4; qq++) {
                int t = t1 * 4 + qq;
                Mf[(size_t)n * 16384 + ((t >> 3) * 256 + c) * 8 + (t & 7)] = f2bf(v[qq]);
            }
        }
    }
}

// ---------------- K4: BN stats -> scale/bias (all-n LDS preload, 2-barrier body) ----------------
__global__ __launch_bounds__(256) void k_stats(const float* __restrict__ M,
                                               const float* __restrict__ P,
                                               const float* __restrict__ rsum,
                                               const float* __restrict__ gamma,
                                               const float* __restrict__ beta,
                                               float* __restrict__ sc,
                                               float* __restrict__ bi) {
    __shared__ float ms[NB][64];     // 4 KB: M rows for this channel, all n
    __shared__ float red[256];
    int c = blockIdx.x;
    int tid = threadIdx.x;
    for (int i = tid; i < NB * 64; i += 256) {
        int n = i >> 6, s = i & 63;
        ms[n][s] = M[((size_t)n * CC + c) * 64 + s];
    }
    __syncthreads();
    // qa = sum_n m_n^T P_n m_n   (each thread strided over the 4096 P-entries per n)
    float qa = 0.f;
    for (int n = 0; n < NB; n++) {
        const float* Pn = P + n * 4096;
#pragma unroll
        for (int p = 0; p < 16; p++) {
            int e = p * 256 + tid;
            qa += ms[n][e >> 6] * ms[n][e & 63] * Pn[e];
        }
    }
    // sa = sum_n sum_s ms[n][s] * rsum[n][s]  (parallel over all 256 threads)
    float sa = 0.f;
    for (int i = tid; i < NB * 64; i += 256) {
        int n = i >> 6, s = i & 63;
        sa += ms[n][s] * rsum[n * SS + s];
    }
    red[tid] = qa;
    __syncthreads();
    for (int off = 128; off > 0; off >>= 1) {
        if (tid < off) red[tid] += red[tid + off];
        __syncthreads();
    }
    float qtot = red[0];
    __syncthreads();
    red[tid] = sa;
    __syncthreads();
    for (int off = 128; off > 0; off >>= 1) {
        if (tid < off) red[tid] += red[tid + off];
        __syncthreads();
    }
    if (tid == 0) {
        float stot = red[0];
        const float invM = 1.0f / ((float)NB * (float)HW);
        float mean = stot * invM;
        float var = qtot * invM - mean * mean;
        float s = gamma[c] * rsqrtf(var + EPS);
        sc[c] = s;
        bi[c] = beta[c] - s * mean;
    }
}

// ---------------- K5: MFMA out: out = x + sc[c]*(M' @ E)[c,k] + bi[c] ----------------
// grid (72, NB): block 256c x 64hw, K=64 (2 MFMA steps). A direct from Mf; B via LDS.
__global__ __launch_bounds__(256) void k_out(const float* __restrict__ x,
                                             const ushort* __restrict__ Mf,
                                             const ushort* __restrict__ Eb,
                                             const float* __restrict__ sc,
                                             const float* __restrict__ bi,
                                             float* __restrict__ out) {
    __shared__ __align__(16) ushort Bl[8 * 64 * 8];    // [kq][n][8] = 8 KB
    int n = blockIdx.y, k0 = blockIdx.x * 64;
    int tid = threadIdx.x, lane = tid & 63, w = tid >> 6;
    int q = lane >> 4, li = lane & 15;
    {
        int nl = tid & 63, pr = tid >> 6;
#pragma unroll
        for (int kk = 0; kk < 2; kk++) {
            int kq = pr * 2 + kk;
            union { ushort u[8]; uint4 v; } tmp;
#pragma unroll
            for (int j = 0; j < 8; j++)
                tmp.u[j] = Eb[((size_t)n * SS + kq * 8 + j) * HW + k0 + nl];
            *(uint4*)&Bl[(kq * 64 + nl) * 8] = tmp.v;
        }
    }
    __syncthreads();
    f32x4 acc[4][4] = {};
#pragma unroll
    for (int ks = 0; ks < 2; ks++) {
        short8 af[4], bfr[4];
#pragma unroll
        for (int mt = 0; mt < 4; mt++) {
            int c = w * 64 + mt * 16 + li;
            uint4 t = *(const uint4*)&Mf[(size_t)n * 16384 + ((ks * 4 + q) * 256 + c) * 8];
            af[mt] = *(short8*)&t;
        }
#pragma unroll
        for (int nt = 0; nt < 4; nt++) {
            int nl = nt * 16 + li;
            uint4 t = *(const uint4*)&Bl[((ks * 4 + q) * 64 + nl) * 8];
            bfr[nt] = *(short8*)&t;
        }
#pragma unroll
        for (int mt = 0; mt < 4; mt++)
#pragma unroll
            for (int nt = 0; nt < 4; nt++)
                acc[mt][nt] = __builtin_amdgcn_mfma_f32_16x16x32_bf16(af[mt], bfr[nt], acc[mt][nt], 0, 0, 0);
    }
#pragma unroll
    for (int mt = 0; mt < 4; mt++) {
#pragma unroll
        for (int rr = 0; rr < 4; rr++) {
            int c = w * 64 + mt * 16 + q * 4 + rr;
            float s_ = sc[c], bv = bi[c];
            size_t base = ((size_t)n * CC + c) * HW + k0;
#pragma unroll
            for (int nt = 0; nt < 4; nt++) {
                int col = nt * 16 + li;
                out[base + col] = x[base + col] + s_ * acc[mt][nt][rr] + bv;
            }
        }
    }
}

extern "C" void kernel_launch(void* const* d_in, const int* in_sizes, int n_in,
                              void* d_out, int out_size, void* d_ws, size_t ws_size,
                              hipStream_t stream) {
    const float* x = (const float*)d_in[0];
    const float* edge = (const float*)d_in[1];
    const float* Ws = (const float*)d_in[2];
    const float* bs = (const float*)d_in[3];
    const float* Wp = (const float*)d_in[4];
    const float* bp = (const float*)d_in[5];
    const float* W1 = (const float*)d_in[6];
    const float* W2 = (const float*)d_in[7];
    const float* We = (const float*)d_in[8];
    const float* gamma = (const float*)d_in[9];
    const float* beta = (const float*)d_in[10];
    float* out = (float*)d_out;

    char* base = (char*)d_ws;
    ushort* Wf  = (ushort*)base;                    base += 65536;           // 64 KB
    ushort* xsb = (ushort*)base;                    base += 9437184;         // 9 MB
    ushort* Eb  = (ushort*)base;                    base += 9437184;
    float*  Up  = (float*)base;                     base += (size_t)NSPLIT * NB * 4096 * 4;
    float*  Pp  = (float*)base;                     base += (size_t)NSPLIT * NB * 4096 * 4;
    float*  U   = (float*)base;                     base += 262144;
    float*  P   = (float*)base;                     base += 262144;
    float*  rsum= (float*)base;                     base += 4096;
    float*  M   = (float*)base;                     base += 1048576;
    ushort* Mf  = (ushort*)base;                    base += 524288;
    float*  sc  = (float*)base;                     base += 1024;
    float*  bi  = (float*)base;                     base += 1024;

    hipMemsetAsync(rsum, 0, 1024 * sizeof(float), stream);
    k_wf<<<128, 256, 0, stream>>>(Ws, Wp, Wf);
    k_proj<<<dim3(72, NB), 256, 0, stream>>>(x, Wf, bs, bp, edge, xsb, Eb, rsum);
    k_graph<<<dim3(NSPLIT, NB), 256, 0, stream>>>(xsb, Eb, Up, Pp);
    k_red<<<128, 256, 0, stream>>>(Up, Pp, U, P);
    k_gcn<<<dim3(NB, 4), 256, 0, stream>>>(U, rsum, W1, W2, We, M, Mf);
    k_stats<<<256, 256, 0, stream>>>(M, P, rsum, gamma, beta, sc, bi);
    k_out<<<dim3(72, NB), 256, 0, stream>>>(x, Mf, Eb, sc, bi, out);
}